// Round 1
// baseline (673.945 us; speedup 1.0000x reference)
//
#include <hip/hip_runtime.h>
#include <math.h>

#define BATCH 8
#define LSEQ  8192
#define HD    256   // H
#define PD    256   // P
#define CHUNK 64
#define NC    (LSEQ/CHUNK)      // 128
#define MROWS (BATCH*LSEQ)      // 65536

#define TM 64
#define TN 64
#define TK 32
#define PADM (TM+4)   // stride 68 floats: rows 16B-aligned (68*4=272 % 16 == 0)

// ---------------- K0a: per-p discretization + A-power table ----------------
__global__ void k_setup(const float* __restrict__ lre_, const float* __restrict__ lim_,
                        const float* __restrict__ lstep,
                        float* __restrict__ coefRe, float* __restrict__ coefIm,
                        float* __restrict__ ApowRe, float* __restrict__ ApowIm) {
    int p = threadIdx.x;
    float lre = lre_[p], lim = lim_[p];
    float dt = expf(lstep[p]);
    float er = lre * dt, ei = lim * dt;          // Lam * Delta
    float ex = expf(er);
    float abr = ex * cosf(ei), abi = ex * sinf(ei);   // Lambda_bar
    // coef = (Lambda_bar - 1) / Lam   (complex divide)
    float nr = abr - 1.0f, ni = abi;
    float den = lre * lre + lim * lim;
    coefRe[p] = (nr * lre + ni * lim) / den;
    coefIm[p] = (ni * lre - nr * lim) / den;
    // Apow[j] = Lambda_bar^j = exp(Lam*Delta*j), j = 0..CHUNK
    for (int j = 0; j <= CHUNK; ++j) {
        float exr = expf(er * (float)j);
        ApowRe[j * PD + p] = exr * cosf(ei * (float)j);
        ApowIm[j * PD + p] = exr * sinf(ei * (float)j);
    }
}

// ---------------- K0b: B_bar = coef * B_tilde ----------------
__global__ void k_bbar(const float* __restrict__ B_ri,
                       const float* __restrict__ coefRe, const float* __restrict__ coefIm,
                       float* __restrict__ BbRe, float* __restrict__ BbIm) {
    int p = blockIdx.x, h = threadIdx.x;
    float cr = coefRe[p], ci = coefIm[p];
    float br = B_ri[((size_t)p * HD + h) * 2 + 0];
    float bi = B_ri[((size_t)p * HD + h) * 2 + 1];
    BbRe[p * HD + h] = cr * br - ci * bi;
    BbIm[p * HD + h] = cr * bi + ci * br;
}

// ---------------- K1: Bu GEMM  (M=B*L, N=P, K=H), B^T layout ----------------
__global__ __launch_bounds__(256) void k_bu(const float* __restrict__ sig,
        const float* __restrict__ BbRe, const float* __restrict__ BbIm,
        float* __restrict__ XRe, float* __restrict__ XIm) {
    __shared__ float As[TK][PADM];
    __shared__ float Brs[TK][PADM];
    __shared__ float Bis[TK][PADM];
    int nwg = gridDim.x;
    int bid = blockIdx.x;
    int w = (bid & 7) * (nwg >> 3) + (bid >> 3);   // bijective XCD swizzle (nwg%8==0)
    int nt = w & 3;           // PD/TN = 4 n-tiles (fast -> same M-slab adjacent)
    int mt = w >> 2;
    int n0 = nt * TN, m0 = mt * TM;
    int t = threadIdx.x;
    int tx = t & 15, ty = t >> 4;
    float accr[4][4] = {{0.f}}, acci[4][4] = {{0.f}};

    for (int k0 = 0; k0 < HD; k0 += TK) {
        #pragma unroll
        for (int it = 0; it < 2; ++it) {
            int idx = (it * 256 + t) * 4;
            int m = idx >> 5, kk = idx & 31;
            float4 va = *(const float4*)&sig[(size_t)(m0 + m) * HD + k0 + kk];
            As[kk + 0][m] = va.x; As[kk + 1][m] = va.y;
            As[kk + 2][m] = va.z; As[kk + 3][m] = va.w;
            float4 vr = *(const float4*)&BbRe[(size_t)(n0 + m) * HD + k0 + kk];
            Brs[kk + 0][m] = vr.x; Brs[kk + 1][m] = vr.y;
            Brs[kk + 2][m] = vr.z; Brs[kk + 3][m] = vr.w;
            float4 vi = *(const float4*)&BbIm[(size_t)(n0 + m) * HD + k0 + kk];
            Bis[kk + 0][m] = vi.x; Bis[kk + 1][m] = vi.y;
            Bis[kk + 2][m] = vi.z; Bis[kk + 3][m] = vi.w;
        }
        __syncthreads();
        #pragma unroll
        for (int kk = 0; kk < TK; ++kk) {
            float4 a4 = *(const float4*)&As[kk][ty * 4];
            float4 r4 = *(const float4*)&Brs[kk][tx * 4];
            float4 i4 = *(const float4*)&Bis[kk][tx * 4];
            float av[4] = {a4.x, a4.y, a4.z, a4.w};
            float rv[4] = {r4.x, r4.y, r4.z, r4.w};
            float iv[4] = {i4.x, i4.y, i4.z, i4.w};
            #pragma unroll
            for (int i = 0; i < 4; ++i)
                #pragma unroll
                for (int j = 0; j < 4; ++j) {
                    accr[i][j] = fmaf(av[i], rv[j], accr[i][j]);
                    acci[i][j] = fmaf(av[i], iv[j], acci[i][j]);
                }
        }
        __syncthreads();
    }
    #pragma unroll
    for (int i = 0; i < 4; ++i) {
        size_t row = (size_t)(m0 + ty * 4 + i) * PD + n0 + tx * 4;
        *(float4*)&XRe[row] = make_float4(accr[i][0], accr[i][1], accr[i][2], accr[i][3]);
        *(float4*)&XIm[row] = make_float4(acci[i][0], acci[i][1], acci[i][2], acci[i][3]);
    }
}

// ---------------- P1: local scan within 64-step chunks (in-place on Bu) ----------------
__global__ __launch_bounds__(256) void k_scan1(float* __restrict__ XRe, float* __restrict__ XIm,
        const float* __restrict__ ApowRe, const float* __restrict__ ApowIm,
        float* __restrict__ endsRe, float* __restrict__ endsIm) {
    int p = threadIdx.x;
    int c = blockIdx.x, b = blockIdx.y;
    float ar = ApowRe[PD + p], ai = ApowIm[PD + p];   // A^1
    float xr = 0.f, xi = 0.f;
    size_t base = ((size_t)b * LSEQ + (size_t)c * CHUNK) * PD + p;
    for (int i = 0; i < CHUNK; ++i) {
        size_t idx = base + (size_t)i * PD;
        float br = XRe[idx], bi = XIm[idx];
        float nr = fmaf(ar, xr, fmaf(-ai, xi, br));
        float ni = fmaf(ar, xi, fmaf(ai, xr, bi));
        xr = nr; xi = ni;
        XRe[idx] = xr; XIm[idx] = xi;
    }
    size_t e = ((size_t)(b * NC + c)) * PD + p;
    endsRe[e] = xr; endsIm[e] = xi;
}

// ---------------- P2: carry scan over chunks (ends -> exclusive carries, in place) ----------
__global__ void k_scan2(float* __restrict__ endsRe, float* __restrict__ endsIm,
                        const float* __restrict__ ApowRe, const float* __restrict__ ApowIm) {
    int p = threadIdx.x, b = blockIdx.x;
    float Ar = ApowRe[CHUNK * PD + p], Ai = ApowIm[CHUNK * PD + p];  // A^CHUNK
    float cr = 0.f, ci = 0.f;
    for (int c = 0; c < NC; ++c) {
        size_t idx = ((size_t)(b * NC + c)) * PD + p;
        float er = endsRe[idx], ei = endsIm[idx];
        endsRe[idx] = cr; endsIm[idx] = ci;           // exclusive prefix = x at chunk entry
        float nr = fmaf(Ar, cr, fmaf(-Ai, ci, er));
        float ni = fmaf(Ar, ci, fmaf(Ai, cr, ei));
        cr = nr; ci = ni;
    }
}

// ---------------- P3: apply carries:  x += A^(i+1) * carry ----------------
__global__ __launch_bounds__(256) void k_apply(float* __restrict__ XRe, float* __restrict__ XIm,
        const float* __restrict__ ApowRe, const float* __restrict__ ApowIm,
        const float* __restrict__ carryRe, const float* __restrict__ carryIm) {
    size_t total = (size_t)MROWS * PD;
    size_t stride = (size_t)gridDim.x * blockDim.x;
    for (size_t e = (size_t)blockIdx.x * blockDim.x + threadIdx.x; e < total; e += stride) {
        int p = (int)(e & (PD - 1));
        size_t row = e >> 8;            // b*L + l
        int l = (int)(row & (LSEQ - 1));
        int bb = (int)(row >> 13);
        int c = l >> 6, i = l & (CHUNK - 1);
        float awr = ApowRe[(i + 1) * PD + p], awi = ApowIm[(i + 1) * PD + p];
        size_t cidx = ((size_t)(bb * NC + c)) * PD + p;
        float cr = carryRe[cidx], ci = carryIm[cidx];
        float xr = XRe[e], xi = XIm[e];
        XRe[e] = fmaf(awr, cr, fmaf(-awi, ci, xr));
        XIm[e] = fmaf(awr, ci, fmaf(awi, cr, xi));
    }
}

// ---------------- K3: readout GEMM  y = Re(x C^T) + D*u  (M=B*L, N=H, K=P) --------------
__global__ __launch_bounds__(256) void k_out(const float* __restrict__ XRe,
        const float* __restrict__ XIm,
        const float* __restrict__ Cre, const float* __restrict__ Cim,
        const float* __restrict__ Dvec, const float* __restrict__ sig,
        float* __restrict__ y) {
    __shared__ float Xrs[TK][PADM];
    __shared__ float Xis[TK][PADM];
    __shared__ float Crs[TK][PADM];
    __shared__ float Cns[TK][PADM];   // negated Cim
    int nwg = gridDim.x;
    int bid = blockIdx.x;
    int w = (bid & 7) * (nwg >> 3) + (bid >> 3);
    int nt = w & 3;          // HD/TN = 4
    int mt = w >> 2;
    int n0 = nt * TN, m0 = mt * TM;
    int t = threadIdx.x;
    int tx = t & 15, ty = t >> 4;
    float acc[4][4] = {{0.f}};

    for (int k0 = 0; k0 < PD; k0 += TK) {
        #pragma unroll
        for (int it = 0; it < 2; ++it) {
            int idx = (it * 256 + t) * 4;
            int m = idx >> 5, kk = idx & 31;
            float4 vr = *(const float4*)&XRe[(size_t)(m0 + m) * PD + k0 + kk];
            Xrs[kk + 0][m] = vr.x; Xrs[kk + 1][m] = vr.y;
            Xrs[kk + 2][m] = vr.z; Xrs[kk + 3][m] = vr.w;
            float4 vi = *(const float4*)&XIm[(size_t)(m0 + m) * PD + k0 + kk];
            Xis[kk + 0][m] = vi.x; Xis[kk + 1][m] = vi.y;
            Xis[kk + 2][m] = vi.z; Xis[kk + 3][m] = vi.w;
            float4 cr = *(const float4*)&Cre[(size_t)(n0 + m) * PD + k0 + kk];
            Crs[kk + 0][m] = cr.x; Crs[kk + 1][m] = cr.y;
            Crs[kk + 2][m] = cr.z; Crs[kk + 3][m] = cr.w;
            float4 ci = *(const float4*)&Cim[(size_t)(n0 + m) * PD + k0 + kk];
            Cns[kk + 0][m] = -ci.x; Cns[kk + 1][m] = -ci.y;
            Cns[kk + 2][m] = -ci.z; Cns[kk + 3][m] = -ci.w;
        }
        __syncthreads();
        #pragma unroll
        for (int kk = 0; kk < TK; ++kk) {
            float4 xr4 = *(const float4*)&Xrs[kk][ty * 4];
            float4 xi4 = *(const float4*)&Xis[kk][ty * 4];
            float4 cr4 = *(const float4*)&Crs[kk][tx * 4];
            float4 cn4 = *(const float4*)&Cns[kk][tx * 4];
            float xrv[4] = {xr4.x, xr4.y, xr4.z, xr4.w};
            float xiv[4] = {xi4.x, xi4.y, xi4.z, xi4.w};
            float crv[4] = {cr4.x, cr4.y, cr4.z, cr4.w};
            float cnv[4] = {cn4.x, cn4.y, cn4.z, cn4.w};
            #pragma unroll
            for (int i = 0; i < 4; ++i)
                #pragma unroll
                for (int j = 0; j < 4; ++j) {
                    acc[i][j] = fmaf(xrv[i], crv[j], acc[i][j]);
                    acc[i][j] = fmaf(xiv[i], cnv[j], acc[i][j]);
                }
        }
        __syncthreads();
    }
    float4 dv = *(const float4*)&Dvec[n0 + tx * 4];
    float dvv[4] = {dv.x, dv.y, dv.z, dv.w};
    #pragma unroll
    for (int i = 0; i < 4; ++i) {
        size_t row = (size_t)(m0 + ty * 4 + i);
        float4 sv = *(const float4*)&sig[row * HD + n0 + tx * 4];
        float svv[4] = {sv.x, sv.y, sv.z, sv.w};
        float4 o;
        o.x = acc[i][0] + dvv[0] * svv[0];
        o.y = acc[i][1] + dvv[1] * svv[1];
        o.z = acc[i][2] + dvv[2] * svv[2];
        o.w = acc[i][3] + dvv[3] * svv[3];
        *(float4*)&y[row * HD + n0 + tx * 4] = o;
    }
}

// ---------------- launcher ----------------
extern "C" void kernel_launch(void* const* d_in, const int* in_sizes, int n_in,
                              void* d_out, int out_size, void* d_ws, size_t ws_size,
                              hipStream_t stream) {
    const float* sig   = (const float*)d_in[0];
    const float* lre   = (const float*)d_in[1];
    const float* lim   = (const float*)d_in[2];
    const float* B_ri  = (const float*)d_in[3];
    const float* Cre   = (const float*)d_in[4];
    const float* Cim   = (const float*)d_in[5];
    const float* Dv    = (const float*)d_in[6];
    const float* lstep = (const float*)d_in[7];
    float* y  = (float*)d_out;
    float* ws = (float*)d_ws;

    size_t MN = (size_t)MROWS * PD;
    float* XRe    = ws;  ws += MN;
    float* XIm    = ws;  ws += MN;
    float* BbRe   = ws;  ws += (size_t)PD * HD;
    float* BbIm   = ws;  ws += (size_t)PD * HD;
    float* coefRe = ws;  ws += PD;
    float* coefIm = ws;  ws += PD;
    float* ApowRe = ws;  ws += (size_t)(CHUNK + 1) * PD;
    float* ApowIm = ws;  ws += (size_t)(CHUNK + 1) * PD;
    float* endsRe = ws;  ws += (size_t)BATCH * NC * PD;
    float* endsIm = ws;  ws += (size_t)BATCH * NC * PD;

    k_setup<<<dim3(1), dim3(PD), 0, stream>>>(lre, lim, lstep, coefRe, coefIm, ApowRe, ApowIm);
    k_bbar<<<dim3(PD), dim3(HD), 0, stream>>>(B_ri, coefRe, coefIm, BbRe, BbIm);
    k_bu<<<dim3((MROWS / TM) * (PD / TN)), dim3(256), 0, stream>>>(sig, BbRe, BbIm, XRe, XIm);
    k_scan1<<<dim3(NC, BATCH), dim3(PD), 0, stream>>>(XRe, XIm, ApowRe, ApowIm, endsRe, endsIm);
    k_scan2<<<dim3(BATCH), dim3(PD), 0, stream>>>(endsRe, endsIm, ApowRe, ApowIm);
    k_apply<<<dim3(4096), dim3(256), 0, stream>>>(XRe, XIm, ApowRe, ApowIm, endsRe, endsIm);
    k_out<<<dim3((MROWS / TM) * (HD / TN)), dim3(256), 0, stream>>>(XRe, XIm, Cre, Cim, Dv, sig, y);
}

// Round 2
// 327.166 us; speedup vs baseline: 2.0599x; 2.0599x over previous
//
#include <hip/hip_runtime.h>
#include <math.h>

#define BATCH 8
#define LSEQ  8192
#define HD    256
#define PD    256
#define CHUNK 64
#define NC    (LSEQ/CHUNK)      // 128
#define MROWS (BATCH*LSEQ)      // 65536
#define XLD   512               // X row stride: interleaved re/im pairs (2p, 2p+1)

typedef short bf16x8 __attribute__((ext_vector_type(8)));
typedef float f32x4  __attribute__((ext_vector_type(4)));

__device__ __forceinline__ void async16(void* l, const void* g) {
    __builtin_amdgcn_global_load_lds((const __attribute__((address_space(1))) void*)g,
                                     (__attribute__((address_space(3))) void*)l, 16, 0, 0);
}

__device__ __forceinline__ unsigned short bf_rne(float f) {
    unsigned u = __float_as_uint(f);
    return (unsigned short)((u + 0x7FFFu + ((u >> 16) & 1u)) >> 16);
}

// ---------------- K0a: per-p discretization + A-power table ----------------
__global__ void k_setup(const float* __restrict__ lre_, const float* __restrict__ lim_,
                        const float* __restrict__ lstep,
                        float* __restrict__ coefRe, float* __restrict__ coefIm,
                        float* __restrict__ ApowRe, float* __restrict__ ApowIm) {
    int p = threadIdx.x;
    float lre = lre_[p], lim = lim_[p];
    float dt = expf(lstep[p]);
    float er = lre * dt, ei = lim * dt;               // Lam * Delta
    float ex = expf(er);
    float abr = ex * cosf(ei), abi = ex * sinf(ei);   // Lambda_bar
    float nr = abr - 1.0f, ni = abi;
    float den = lre * lre + lim * lim;
    coefRe[p] = (nr * lre + ni * lim) / den;
    coefIm[p] = (ni * lre - nr * lim) / den;
    for (int j = 0; j <= CHUNK; ++j) {
        float exr = expf(er * (float)j);
        ApowRe[j * PD + p] = exr * cosf(ei * (float)j);
        ApowIm[j * PD + p] = exr * sinf(ei * (float)j);
    }
}

// ---------------- K0b: Bcat[512][256] bf16 hi/lo  (row 2p = re, 2p+1 = im) --------
__global__ void k_bbar(const float* __restrict__ B_ri,
                       const float* __restrict__ coefRe, const float* __restrict__ coefIm,
                       unsigned short* __restrict__ BcH, unsigned short* __restrict__ BcL) {
    int p = blockIdx.x, h = threadIdx.x;
    float cr = coefRe[p], ci = coefIm[p];
    float br = B_ri[((size_t)p * HD + h) * 2 + 0];
    float bi = B_ri[((size_t)p * HD + h) * 2 + 1];
    float re = cr * br - ci * bi;
    float im = cr * bi + ci * br;
    unsigned ur = __float_as_uint(re), ui = __float_as_uint(im);
    unsigned short hr = (unsigned short)(ur >> 16), hi_ = (unsigned short)(ui >> 16);
    float rr = re - __uint_as_float(ur & 0xFFFF0000u);
    float ri = im - __uint_as_float(ui & 0xFFFF0000u);
    BcH[(size_t)(2 * p) * HD + h]     = hr;
    BcL[(size_t)(2 * p) * HD + h]     = (unsigned short)(__float_as_uint(rr) >> 16);
    BcH[(size_t)(2 * p + 1) * HD + h] = hi_;
    BcL[(size_t)(2 * p + 1) * HD + h] = (unsigned short)(__float_as_uint(ri) >> 16);
}

// ---------------- K0c: Ccat[256][512] bf16 hi/lo (col 2p = Cre, 2p+1 = -Cim) ------
__global__ void k_ccat(const float* __restrict__ Cre, const float* __restrict__ Cim,
                       unsigned short* __restrict__ CcH, unsigned short* __restrict__ CcL) {
    int h = blockIdx.x, p = threadIdx.x;
    float re = Cre[(size_t)h * PD + p];
    float im = -Cim[(size_t)h * PD + p];
    unsigned ur = __float_as_uint(re), ui = __float_as_uint(im);
    float rr = re - __uint_as_float(ur & 0xFFFF0000u);
    float ri = im - __uint_as_float(ui & 0xFFFF0000u);
    CcH[(size_t)h * XLD + 2 * p]     = (unsigned short)(ur >> 16);
    CcL[(size_t)h * XLD + 2 * p]     = (unsigned short)(__float_as_uint(rr) >> 16);
    CcH[(size_t)h * XLD + 2 * p + 1] = (unsigned short)(ui >> 16);
    CcL[(size_t)h * XLD + 2 * p + 1] = (unsigned short)(__float_as_uint(ri) >> 16);
}

// ---------------- MFMA GEMM template: out[M][ND] = A[M][KD] * B[ND][KD]^T ----------
// A fp32 (reg-staged, split to bf16 hi(+lo)); B bf16 hi/lo via global_load_lds.
// 128x128 tile, BK=64, 4 waves (2x2), 16x16x32 MFMA, wave-tile 64x64 (4x4 frags).
template<int ND, int KD, bool HAS_AL, bool EPI>
__global__ __launch_bounds__(256, 2) void gemm_split(
        const float* __restrict__ A,
        const unsigned short* __restrict__ Bh, const unsigned short* __restrict__ Bl,
        float* __restrict__ out,
        const float* __restrict__ Dvec, const float* __restrict__ sig) {
    __shared__ unsigned short AhS[128 * 64];
    __shared__ unsigned short AlS[HAS_AL ? 128 * 64 : 8];
    __shared__ unsigned short BhS[128 * 64];
    __shared__ unsigned short BlS[128 * 64];

    int nwg = gridDim.x;
    int bid = blockIdx.x;
    int w = (bid & 7) * (nwg >> 3) + (bid >> 3);   // bijective XCD swizzle (nwg%8==0)
    constexpr int NT = ND / 128;
    int nt = w % NT, mt = w / NT;
    int m0 = mt * 128, n0 = nt * 128;
    int t = threadIdx.x;
    int l = t & 63;
    int wv = t >> 6;
    int wm = wv & 1, wn = wv >> 1;
    int lr = l & 15, kg = l >> 4;          // frag row / k-octet group
    int wbase = (t & 0xC0) * 8;            // wave-uniform LDS chunk base (elements)

    f32x4 acc[4][4] = {};

    for (int k0 = 0; k0 < KD; k0 += 64) {
        // ---- stage B (hi+lo) via async global->LDS, 16B chunks ----
        #pragma unroll
        for (int i = 0; i < 4; ++i) {
            int j = i * 256 + t;
            int r = j >> 3, c = (j & 7) * 8;
            int lbase = i * 2048 + wbase;            // (i*256 + wave*64) chunks * 8 elems
            const size_t go = (size_t)(n0 + r) * KD + k0 + c;
            async16(&BhS[lbase], &Bh[go]);
            async16(&BlS[lbase], &Bl[go]);
        }
        // ---- stage A: fp32 load -> split bf16 -> LDS ----
        #pragma unroll
        for (int i = 0; i < 8; ++i) {
            int idx = i * 1024 + t * 4;
            int r = idx >> 6, c = idx & 63;
            float4 v = *(const float4*)&A[(size_t)(m0 + r) * KD + k0 + c];
            unsigned u0 = __float_as_uint(v.x), u1 = __float_as_uint(v.y),
                     u2 = __float_as_uint(v.z), u3 = __float_as_uint(v.w);
            if constexpr (HAS_AL) {
                // truncation split: hi = trunc(f), lo = bf16(f - hi); pair error ~2^-16
                *(ushort4*)&AhS[r * 64 + c] = make_ushort4(
                    (unsigned short)(u0 >> 16), (unsigned short)(u1 >> 16),
                    (unsigned short)(u2 >> 16), (unsigned short)(u3 >> 16));
                float r0 = v.x - __uint_as_float(u0 & 0xFFFF0000u);
                float r1 = v.y - __uint_as_float(u1 & 0xFFFF0000u);
                float r2 = v.z - __uint_as_float(u2 & 0xFFFF0000u);
                float r3 = v.w - __uint_as_float(u3 & 0xFFFF0000u);
                *(ushort4*)&AlS[r * 64 + c] = make_ushort4(
                    (unsigned short)(__float_as_uint(r0) >> 16),
                    (unsigned short)(__float_as_uint(r1) >> 16),
                    (unsigned short)(__float_as_uint(r2) >> 16),
                    (unsigned short)(__float_as_uint(r3) >> 16));
            } else {
                // hi-only: round-to-nearest-even
                *(ushort4*)&AhS[r * 64 + c] = make_ushort4(
                    bf_rne(v.x), bf_rne(v.y), bf_rne(v.z), bf_rne(v.w));
            }
        }
        __syncthreads();   // drains vmcnt (async B) + lgkm (A ds_writes)
        // ---- compute ----
        #pragma unroll
        for (int kk = 0; kk < 2; ++kk) {
            int ko = kk * 32 + kg * 8;
            bf16x8 ah[4], al[4], bh[4], bl[4];
            #pragma unroll
            for (int i = 0; i < 4; ++i) {
                int ro = (wm * 64 + i * 16 + lr) * 64 + ko;
                ah[i] = *(const bf16x8*)&AhS[ro];
                if constexpr (HAS_AL) al[i] = *(const bf16x8*)&AlS[ro];
            }
            #pragma unroll
            for (int j = 0; j < 4; ++j) {
                int ro = (wn * 64 + j * 16 + lr) * 64 + ko;
                bh[j] = *(const bf16x8*)&BhS[ro];
                bl[j] = *(const bf16x8*)&BlS[ro];
            }
            #pragma unroll
            for (int i = 0; i < 4; ++i)
                #pragma unroll
                for (int j = 0; j < 4; ++j) {
                    acc[i][j] = __builtin_amdgcn_mfma_f32_16x16x32_bf16(ah[i], bh[j], acc[i][j], 0, 0, 0);
                    acc[i][j] = __builtin_amdgcn_mfma_f32_16x16x32_bf16(ah[i], bl[j], acc[i][j], 0, 0, 0);
                    if constexpr (HAS_AL)
                        acc[i][j] = __builtin_amdgcn_mfma_f32_16x16x32_bf16(al[i], bh[j], acc[i][j], 0, 0, 0);
                }
        }
        __syncthreads();
    }
    // ---- epilogue: C/D layout col=lane&15, row=(lane>>4)*4+q ----
    #pragma unroll
    for (int i = 0; i < 4; ++i) {
        #pragma unroll
        for (int j = 0; j < 4; ++j) {
            int n = n0 + wn * 64 + j * 16 + lr;
            float dn = 0.f;
            if constexpr (EPI) dn = Dvec[n];
            #pragma unroll
            for (int q = 0; q < 4; ++q) {
                int m = m0 + wm * 64 + i * 16 + kg * 4 + q;
                float o = acc[i][j][q];
                if constexpr (EPI) o += dn * sig[(size_t)m * HD + n];
                out[(size_t)m * ND + n] = o;
            }
        }
    }
}

// ---------------- P1: chunk-end states only (read Bu once) ----------------
__global__ __launch_bounds__(256) void k_ends(const float* __restrict__ X,
        const float* __restrict__ ApowRe, const float* __restrict__ ApowIm,
        float* __restrict__ ends) {
    int p = threadIdx.x;
    int c = blockIdx.x & (NC - 1), b = blockIdx.x >> 7;
    float ar = ApowRe[PD + p], ai = ApowIm[PD + p];    // A^1
    float xr = 0.f, xi = 0.f;
    size_t base = ((size_t)b * LSEQ + (size_t)c * CHUNK) * XLD + 2 * p;
    #pragma unroll 8
    for (int i = 0; i < CHUNK; ++i) {
        float2 u = *(const float2*)&X[base + (size_t)i * XLD];
        float nr = fmaf(ar, xr, fmaf(-ai, xi, u.x));
        float ni = fmaf(ar, xi, fmaf(ai, xr, u.y));
        xr = nr; xi = ni;
    }
    *(float2*)&ends[((size_t)(b * NC + c)) * XLD + 2 * p] = make_float2(xr, xi);
}

// ---------------- P2: carry scan over chunks (in-place -> exclusive) ----------------
__global__ void k_scan2(float* __restrict__ ends,
                        const float* __restrict__ ApowRe, const float* __restrict__ ApowIm) {
    int p = threadIdx.x, b = blockIdx.x;
    float Ar = ApowRe[CHUNK * PD + p], Ai = ApowIm[CHUNK * PD + p];  // A^CHUNK
    float cr = 0.f, ci = 0.f;
    #pragma unroll 4
    for (int c = 0; c < NC; ++c) {
        size_t idx = ((size_t)(b * NC + c)) * XLD + 2 * p;
        float2 e = *(const float2*)&ends[idx];
        *(float2*)&ends[idx] = make_float2(cr, ci);
        float nr = fmaf(Ar, cr, fmaf(-Ai, ci, e.x));
        float ni = fmaf(Ar, ci, fmaf(Ai, cr, e.y));
        cr = nr; ci = ni;
    }
}

// ---------------- P3: recompute local scan with carry, write X in place ----------------
__global__ __launch_bounds__(256) void k_scan3(float* __restrict__ X,
        const float* __restrict__ ApowRe, const float* __restrict__ ApowIm,
        const float* __restrict__ carry) {
    int p = threadIdx.x;
    int c = blockIdx.x & (NC - 1), b = blockIdx.x >> 7;
    float ar = ApowRe[PD + p], ai = ApowIm[PD + p];    // A^1
    float2 cv = *(const float2*)&carry[((size_t)(b * NC + c)) * XLD + 2 * p];
    float xr = cv.x, xi = cv.y;
    size_t base = ((size_t)b * LSEQ + (size_t)c * CHUNK) * XLD + 2 * p;
    #pragma unroll 8
    for (int i = 0; i < CHUNK; ++i) {
        size_t idx = base + (size_t)i * XLD;
        float2 u = *(const float2*)&X[idx];
        float nr = fmaf(ar, xr, fmaf(-ai, xi, u.x));
        float ni = fmaf(ar, xi, fmaf(ai, xr, u.y));
        xr = nr; xi = ni;
        *(float2*)&X[idx] = make_float2(xr, xi);
    }
}

// ---------------- launcher ----------------
extern "C" void kernel_launch(void* const* d_in, const int* in_sizes, int n_in,
                              void* d_out, int out_size, void* d_ws, size_t ws_size,
                              hipStream_t stream) {
    const float* sig   = (const float*)d_in[0];
    const float* lre   = (const float*)d_in[1];
    const float* lim   = (const float*)d_in[2];
    const float* B_ri  = (const float*)d_in[3];
    const float* Cre   = (const float*)d_in[4];
    const float* Cim   = (const float*)d_in[5];
    const float* Dv    = (const float*)d_in[6];
    const float* lstep = (const float*)d_in[7];
    float* y = (float*)d_out;
    (void)in_sizes; (void)n_in; (void)out_size; (void)ws_size;

    char* base = (char*)d_ws;
    float* X      = (float*)base; base += (size_t)MROWS * XLD * 4;      // 128 MB
    float* ends   = (float*)base; base += (size_t)BATCH * NC * XLD * 4; // 2 MB
    float* ApowRe = (float*)base; base += (size_t)(CHUNK + 1) * PD * 4;
    float* ApowIm = (float*)base; base += (size_t)(CHUNK + 1) * PD * 4;
    float* coefRe = (float*)base; base += PD * 4;
    float* coefIm = (float*)base; base += PD * 4;
    unsigned short* BcH = (unsigned short*)base; base += (size_t)XLD * HD * 2;
    unsigned short* BcL = (unsigned short*)base; base += (size_t)XLD * HD * 2;
    unsigned short* CcH = (unsigned short*)base; base += (size_t)HD * XLD * 2;
    unsigned short* CcL = (unsigned short*)base; base += (size_t)HD * XLD * 2;

    k_setup<<<dim3(1), dim3(PD), 0, stream>>>(lre, lim, lstep, coefRe, coefIm, ApowRe, ApowIm);
    k_bbar<<<dim3(PD), dim3(HD), 0, stream>>>(B_ri, coefRe, coefIm, BcH, BcL);
    k_ccat<<<dim3(HD), dim3(PD), 0, stream>>>(Cre, Cim, CcH, CcL);
    // G1: X = sig @ Bcat^T   (split A + split B, 3 products)
    gemm_split<XLD, HD, true, false><<<dim3((MROWS / 128) * (XLD / 128)), dim3(256), 0, stream>>>(
        sig, BcH, BcL, X, nullptr, nullptr);
    k_ends<<<dim3(NC * BATCH), dim3(PD), 0, stream>>>(X, ApowRe, ApowIm, ends);
    k_scan2<<<dim3(BATCH), dim3(PD), 0, stream>>>(ends, ApowRe, ApowIm);
    k_scan3<<<dim3(NC * BATCH), dim3(PD), 0, stream>>>(X, ApowRe, ApowIm, ends);
    // G2: y = X @ Ccat^T + D*u   (plain A, split B, 2 products)
    gemm_split<HD, XLD, false, true><<<dim3((MROWS / 128) * (HD / 128)), dim3(256), 0, stream>>>(
        X, CcH, CcL, y, Dv, sig);
}